// Round 12
// baseline (182.817 us; speedup 1.0000x reference)
//
#include <hip/hip_runtime.h>
#include <stdint.h>

typedef __attribute__((ext_vector_type(8))) short short8;   // 8 bf16 (bit pattern)
typedef __attribute__((ext_vector_type(4))) short short4v;  // 4 bf16
typedef __attribute__((ext_vector_type(4))) float f32x4;

static constexpr int BB = 2, NN = 20000, UU = 100;
static constexpr int MT = BB * NN;       // 40000 node-rows
static constexpr int MPAD = 40192;       // 157 * 256
static constexpr float NEG = 0.2f;

__device__ __forceinline__ float b2f(short s) {
  union { uint32_t u; float f; } cv; cv.u = ((uint32_t)(uint16_t)s) << 16; return cv.f;
}
__device__ __forceinline__ short f2b(float x) {             // RNE f32->bf16
  union { float f; uint32_t u; } cv; cv.f = x;
  uint32_t r = cv.u + 0x7FFFu + ((cv.u >> 16) & 1u);
  return (short)(r >> 16);
}

// DPP row_ror add: x += rotate-within-16-lanes(x). VALU-latency lane exchange.
template<int CTRL>
__device__ __forceinline__ float dppadd(float x) {
  int v = __builtin_amdgcn_update_dpp(0, __float_as_int(x), CTRL, 0xF, 0xF, false);
  return x + __int_as_float(v);
}
// sum over each 32-lane half: 4 DPP ror stages (16-lane sum) + 1 xor16
__device__ __forceinline__ float red32(float x) {
  x = dppadd<0x121>(x);   // row_ror:1
  x = dppadd<0x122>(x);   // row_ror:2
  x = dppadd<0x124>(x);   // row_ror:4
  x = dppadd<0x128>(x);   // row_ror:8
  return x + __shfl_xor(x, 16);
}

// ---------------- fused prep: zero cursor + build A1 + build BT1/BT2 (all LINEAR) ----

__global__ void k_prep(const float* __restrict__ inp, const float* __restrict__ st,
                       const float* __restrict__ Wl1, const float* __restrict__ Wr1,
                       const float* __restrict__ Wl2, const float* __restrict__ Wr2,
                       short* __restrict__ A, short* __restrict__ BT1,
                       short* __restrict__ BT2, int* __restrict__ cursor) {
  int t = blockIdx.x * 256 + threadIdx.x;
  if (t < MT * 16) {              // A1 row r: e0=inp, e1..100=state, pad 0
    int r = t >> 4, g = t & 15;
    short8 v;
#pragma unroll
    for (int j = 0; j < 8; ++j) {
      int e = g * 8 + j;
      float x = 0.f;
      if (e == 0) x = inp[r];
      else if (e <= 100) x = st[(size_t)r * 100 + e - 1];
      v[j] = f2b(x);
    }
    *(short8*)(A + (size_t)r * 128 + (g << 3)) = v;
  }
  if (t < 512 * 16) {             // BT1 (SPLIT=200)
    int n = t >> 4, g = t & 15;
    short8 v;
#pragma unroll
    for (int j = 0; j < 8; ++j) {
      int k = g * 8 + j;
      float x = 0.f;
      if (k < 101 && n < 400)
        x = (n < 200) ? Wl1[(size_t)k * 200 + n] : Wr1[(size_t)k * 200 + n - 200];
      v[j] = f2b(x);
    }
    *(short8*)(BT1 + (size_t)n * 128 + (g << 3)) = v;
  }
  if (t < 256 * 16) {             // BT2 (rot: k<100 -> W[k+1], k==100 -> W[0])
    int n = t >> 4, g = t & 15;
    short8 v;
#pragma unroll
    for (int j = 0; j < 8; ++j) {
      int k = g * 8 + j;
      int ksrc = (k < 100) ? k + 1 : ((k == 100) ? 0 : -1);
      float x = 0.f;
      if (ksrc >= 0 && n < 200)
        x = (n < 100) ? Wl2[(size_t)ksrc * 100 + n] : Wr2[(size_t)ksrc * 100 + n - 100];
      v[j] = f2b(x);
    }
    *(short8*)(BT2 + (size_t)n * 128 + (g << 3)) = v;
  }
  if (t < NN) cursor[t] = 0;
}

// ---------------- CSR build ----------------

__global__ __launch_bounds__(1024) void k_scan(int* __restrict__ histcur,
                                               int* __restrict__ rowptr, int N, int E) {
  __shared__ int part[1024];
  int t = threadIdx.x;
  int CH = (N + 1023) / 1024;
  int beg = t * CH; if (beg > N) beg = N;
  int end = beg + CH; if (end > N) end = N;
  int s = 0;
  for (int i = beg; i < end; ++i) s += histcur[i];
  part[t] = s;
  __syncthreads();
  for (int off = 1; off < 1024; off <<= 1) {
    int v = (t >= off) ? part[t - off] : 0;
    __syncthreads();
    part[t] += v;
    __syncthreads();
  }
  int base = (t == 0) ? 0 : part[t - 1];
  for (int i = beg; i < end; ++i) {
    int h = histcur[i];
    rowptr[i] = base;
    histcur[i] = base;
    base += h;
  }
  if (t == 1023) rowptr[N] = part[1023];
}

__global__ void k_scatter(const int* __restrict__ src, const int* __restrict__ dst, int E,
                          int* __restrict__ cursor, int* __restrict__ col) {
  int e = blockIdx.x * 256 + threadIdx.x;
  if (e < E) {
    int p = atomicAdd(&cursor[dst[e]], 1);
    col[p] = src[e];
  }
}

// ---------------- no-LDS direct-fragment MFMA GEMM, swapped operands ----------------
// K=128 = 4 k-frags; fragments contiguous 16B in row-major global. Wave: 64 rows x
// (NTW*64) cols. acc = mfma(B_frag, A_frag, acc): output row=channel, col=node ->
// each lane stores 4 consecutive channels of one node as short4 (8B).
// A-frags persist in registers across n-tiles. Trailing blocks (>= nbg) run the
// edge histogram (layer-1 launch only).
// X row (per node, 4*SPLIT shorts): [xl_b0 | xl_b1 | xr_b0 | xr_b1].

template<int NOUT, int SPLIT, int NTW>
__global__ __launch_bounds__(256) void k_gemmd(
    const short* __restrict__ A, const short* __restrict__ BT,
    const float* __restrict__ bias_l, const float* __restrict__ bias_r,
    short* __restrict__ X, int nbg,
    const int* __restrict__ dstE, int E, int* __restrict__ hist) {
  int tid = threadIdx.x;
  if ((int)blockIdx.x >= nbg) {   // fused histogram blocks
    int e = (blockIdx.x - nbg) * 256 + tid;
    if (e < E) atomicAdd(&hist[dstE[e]], 1);
    return;
  }
  int bx = blockIdx.x % 157, by = blockIdx.x / 157;
  int w = tid >> 6, lane = tid & 63;
  int m0 = (bx * 4 + w) * 64;
  int lrow = lane & 15, lk = lane >> 4;

  short8 a[4][4];                 // [kk][j] node fragments, persist across n-tiles
#pragma unroll
  for (int kk = 0; kk < 4; ++kk)
#pragma unroll
    for (int j = 0; j < 4; ++j)
      a[kk][j] = *(const short8*)(A + ((size_t)m0 + j * 16 + lrow) * 128 + lk * 8 + kk * 32);

#pragma unroll
  for (int nt = 0; nt < NTW; ++nt) {
    int nbase = (by * NTW + nt) * 64;
    f32x4 acc[4][4];              // [i=ch-subtile][j=node-subtile]
#pragma unroll
    for (int i = 0; i < 4; ++i)
#pragma unroll
      for (int j = 0; j < 4; ++j) acc[i][j] = (f32x4){0.f, 0.f, 0.f, 0.f};

#pragma unroll
    for (int kk = 0; kk < 4; ++kk) {
      short8 b[4];
#pragma unroll
      for (int i = 0; i < 4; ++i)
        b[i] = *(const short8*)(BT + ((size_t)nbase + i * 16 + lrow) * 128 + lk * 8 + kk * 32);
#pragma unroll
      for (int i = 0; i < 4; ++i)
#pragma unroll
        for (int j = 0; j < 4; ++j)
          acc[i][j] = __builtin_amdgcn_mfma_f32_16x16x32_bf16(b[i], a[kk][j], acc[i][j], 0, 0, 0);
    }

#pragma unroll
    for (int i = 0; i < 4; ++i) {
      int ch = nbase + i * 16 + lk * 4;       // 4 consecutive channels (ch..ch+3)
      if (ch < NOUT) {
        f32x4 bv = (ch < SPLIT) ? *(const f32x4*)(bias_l + ch)
                                : *(const f32x4*)(bias_r + (ch - SPLIT));
        int cbase = (ch < SPLIT) ? ch : 2 * SPLIT + (ch - SPLIT);
#pragma unroll
        for (int j = 0; j < 4; ++j) {
          int m = m0 + j * 16 + lrow;
          if (m < MT) {
            int b_   = (m >= NN) ? 1 : 0;
            int node = m - b_ * NN;
            short4v wv;
#pragma unroll
            for (int r = 0; r < 4; ++r) wv[r] = f2b(acc[i][j][r] + bv[r]);
            *(short4v*)(X + (size_t)node * (4 * SPLIT) + cbase + b_ * SPLIT) = wv;
          }
        }
      }
    }
  }
}

// ---------------- GATv2 aggregation: PERSISTENT waves, 2-edge unroll, DPP reduce ----
// Fixed grid; each wave grid-strides over dsts. att/bg/bias hoisted out of loop.
// lanes 0-31 = batch 0, 32-63 = batch 1; lane owns 8 (agg1) / 4 (agg2) channels.
// No-max softmax: logits bounded (|e| << 88), exp safe in fp32.

#define EDGE1(S, NUM, DEN, NCH, STRIDE)                                            \
  { short8 v_ = *(const short8*)(xb + (size_t)(S) * STRIDE);                       \
    float e_ = 0.f;                                                                \
    _Pragma("unroll") for (int q = 0; q < NCH; ++q) {                              \
      float x_ = b2f(v_[q]); float m_ = x_ + xrv[q];                               \
      m_ = (m_ > 0.f) ? m_ : NEG * m_; e_ = fmaf(m_, attv[q], e_); }               \
    e_ = red32(e_);                                                                \
    float p_ = __expf(e_); DEN += p_;                                              \
    _Pragma("unroll") for (int q = 0; q < NCH; ++q)                                \
      NUM[q] = fmaf(p_, b2f(v_[q]), NUM[q]); }

__global__ __launch_bounds__(256) void k_agg1(
    const short* __restrict__ X1, const int* __restrict__ rowptr, const int* __restrict__ col,
    const float* __restrict__ att, const float* __restrict__ bgv, const float* __restrict__ bias0,
    const float* __restrict__ st, const float* __restrict__ inp,
    short* __restrict__ A2, float* __restrict__ uu) {
  int lane = threadIdx.x & 63;
  int gw = blockIdx.x * 4 + (threadIdx.x >> 6);
  int NW = gridDim.x * 4;
  int half = lane >> 5, ll = lane & 31;
  int c0 = (ll < 25 ? ll : 24) * 8;
  const short* xb = X1 + (size_t)half * 200 + c0;   // + s*800 per src node

  float attv[8];
  f32x4 g0 = (f32x4){0,0,0,0}, g1 = (f32x4){0,0,0,0};
  f32x4 h0 = (f32x4){0,0,0,0}, h1 = (f32x4){0,0,0,0};
  {
    f32x4 a0 = (f32x4){0,0,0,0}, a1 = (f32x4){0,0,0,0};
    if (ll < 25) {
      a0 = *(const f32x4*)(att + c0);   a1 = *(const f32x4*)(att + c0 + 4);
      g0 = *(const f32x4*)(bgv + c0);   g1 = *(const f32x4*)(bgv + c0 + 4);
      h0 = *(const f32x4*)(bias0 + c0); h1 = *(const f32x4*)(bias0 + c0 + 4);
    }
#pragma unroll
    for (int q = 0; q < 4; ++q) { attv[q] = a0[q]; attv[4 + q] = a1[q]; }
  }

  for (int n = gw; n < NN; n += NW) {
    int idx = half * NN + n;
    float xrv[8], num[8];
    {
      short8 xr8 = *(const short8*)(X1 + (size_t)n * 800 + 400 + half * 200 + c0);
#pragma unroll
      for (int q = 0; q < 8; ++q) xrv[q] = (ll < 25) ? b2f(xr8[q]) : 0.f;
    }
    float denom;
    { // self-loop (src = n)
      short8 v = *(const short8*)(xb + (size_t)n * 800);
      float xs[8], e = 0.f;
#pragma unroll
      for (int q = 0; q < 8; ++q) {
        xs[q] = b2f(v[q]);
        float msg = xs[q] + xrv[q];
        msg = (msg > 0.f) ? msg : NEG * msg;
        e = fmaf(msg, attv[q], e);
      }
      e = red32(e);
      float pe = __expf(e);
      denom = pe;
#pragma unroll
      for (int q = 0; q < 8; ++q) num[q] = pe * xs[q];
    }

    int beg = rowptr[n], end = rowptr[n + 1];
    int deg = end - beg;
    int degc = min(deg, 64);
    int cv = 0;
    if (deg > 0) cv = col[beg + (lane < degc ? lane : 0)];
    int p = 0;
    for (; p + 2 <= degc; p += 2) {          // 2 independent chains
      int s0 = __shfl(cv, p), s1 = __shfl(cv, p + 1);
      short8 v0 = *(const short8*)(xb + (size_t)s0 * 800);
      short8 v1 = *(const short8*)(xb + (size_t)s1 * 800);
      float e0 = 0.f, e1 = 0.f;
#pragma unroll
      for (int q = 0; q < 8; ++q) {
        float x, m_;
        x = b2f(v0[q]); m_ = x + xrv[q]; m_ = (m_ > 0.f) ? m_ : NEG * m_; e0 = fmaf(m_, attv[q], e0);
        x = b2f(v1[q]); m_ = x + xrv[q]; m_ = (m_ > 0.f) ? m_ : NEG * m_; e1 = fmaf(m_, attv[q], e1);
      }
      e0 = red32(e0); e1 = red32(e1);
      float pe0 = __expf(e0), pe1 = __expf(e1);
      denom += pe0 + pe1;
#pragma unroll
      for (int q = 0; q < 8; ++q)
        num[q] = fmaf(pe1, b2f(v1[q]), fmaf(pe0, b2f(v0[q]), num[q]));
    }
    if (p < degc) {
      int s0 = __shfl(cv, p);
      EDGE1(s0, num, denom, 8, 800);
    }
    for (int t = 64; t < deg; ++t) { int s = col[beg + t]; EDGE1(s, num, denom, 8, 800); }

    float invd = 1.f / denom;
    if (ll < 25) {
      float vq[8];
#pragma unroll
      for (int q = 0; q < 4; ++q) {
        float o0 = fmaf(num[q], invd, g0[q] + h0[q]);
        vq[q] = 1.f / (1.f + __expf(-o0));
        float o1 = fmaf(num[4 + q], invd, g1[q] + h1[q]);
        vq[4 + q] = 1.f / (1.f + __expf(-o1));
      }
      size_t sb = (size_t)idx * UU;
      if (ll < 12) {                       // 8 r*state channels -> A2 granule ll (linear)
        f32x4 s0 = *(const f32x4*)(st + sb + c0), s1 = *(const f32x4*)(st + sb + c0 + 4);
        short8 wv;
#pragma unroll
        for (int q = 0; q < 4; ++q) { wv[q] = f2b(vq[q] * s0[q]); wv[4 + q] = f2b(vq[4 + q] * s1[q]); }
        *(short8*)(A2 + (size_t)idx * 128 + (ll << 3)) = wv;
      } else if (ll == 12) {               // ch 96-99 rs + elem100 = inp + pad
        f32x4 s0 = *(const f32x4*)(st + sb + 96);
        short8 wv;
#pragma unroll
        for (int q = 0; q < 4; ++q) wv[q] = f2b(vq[q] * s0[q]);
        wv[4] = f2b(inp[idx]); wv[5] = 0; wv[6] = 0; wv[7] = 0;
        *(short8*)(A2 + (size_t)idx * 128 + (12 << 3)) = wv;
        *(f32x4*)(uu + sb) = (f32x4){vq[4], vq[5], vq[6], vq[7]};
      } else {                             // 8 u channels; ll 13-15 also zero-pad A2
        int uo = c0 - 100;
        *(f32x4*)(uu + sb + uo)     = (f32x4){vq[0], vq[1], vq[2], vq[3]};
        *(f32x4*)(uu + sb + uo + 4) = (f32x4){vq[4], vq[5], vq[6], vq[7]};
        if (ll < 16) {
          short8 z = (short8){0,0,0,0,0,0,0,0};
          *(short8*)(A2 + (size_t)idx * 128 + (ll << 3)) = z;
        }
      }
    }
  }
}

__global__ __launch_bounds__(256) void k_agg2(
    const short* __restrict__ X2, const int* __restrict__ rowptr, const int* __restrict__ col,
    const float* __restrict__ att, const float* __restrict__ bgv, const float* __restrict__ bias1,
    const float* __restrict__ st, float* __restrict__ out) {
  int lane = threadIdx.x & 63;
  int gw = blockIdx.x * 4 + (threadIdx.x >> 6);
  int NW = gridDim.x * 4;
  int half = lane >> 5, ll = lane & 31;
  int c0 = (ll < 25 ? ll : 24) * 4;
  const short* xb = X2 + (size_t)half * 100 + c0;   // + s*400 per src node

  float attv[4];
  f32x4 g0 = (f32x4){0,0,0,0}, h0 = (f32x4){0,0,0,0};
  {
    f32x4 a0 = (f32x4){0,0,0,0};
    if (ll < 25) {
      a0 = *(const f32x4*)(att + c0);
      g0 = *(const f32x4*)(bgv + c0);
      h0 = *(const f32x4*)(bias1 + c0);
    }
#pragma unroll
    for (int q = 0; q < 4; ++q) attv[q] = a0[q];
  }

  for (int n = gw; n < NN; n += NW) {
    int idx = half * NN + n;
    float xrv[4], num[4];
    {
      short4v xr4 = *(const short4v*)(X2 + (size_t)n * 400 + 200 + half * 100 + c0);
#pragma unroll
      for (int q = 0; q < 4; ++q) xrv[q] = (ll < 25) ? b2f(xr4[q]) : 0.f;
    }
    float denom;
    { // self-loop
      short4v v = *(const short4v*)(xb + (size_t)n * 400);
      float xs[4], e = 0.f;
#pragma unroll
      for (int q = 0; q < 4; ++q) {
        xs[q] = b2f(v[q]);
        float msg = xs[q] + xrv[q];
        msg = (msg > 0.f) ? msg : NEG * msg;
        e = fmaf(msg, attv[q], e);
      }
      e = red32(e);
      float pe = __expf(e);
      denom = pe;
#pragma unroll
      for (int q = 0; q < 4; ++q) num[q] = pe * xs[q];
    }

    int beg = rowptr[n], end = rowptr[n + 1];
    int deg = end - beg;
    int degc = min(deg, 64);
    int cv = 0;
    if (deg > 0) cv = col[beg + (lane < degc ? lane : 0)];
    int p = 0;
    for (; p + 2 <= degc; p += 2) {
      int s0 = __shfl(cv, p), s1 = __shfl(cv, p + 1);
      short4v v0 = *(const short4v*)(xb + (size_t)s0 * 400);
      short4v v1 = *(const short4v*)(xb + (size_t)s1 * 400);
      float e0 = 0.f, e1 = 0.f;
#pragma unroll
      for (int q = 0; q < 4; ++q) {
        float x, m_;
        x = b2f(v0[q]); m_ = x + xrv[q]; m_ = (m_ > 0.f) ? m_ : NEG * m_; e0 = fmaf(m_, attv[q], e0);
        x = b2f(v1[q]); m_ = x + xrv[q]; m_ = (m_ > 0.f) ? m_ : NEG * m_; e1 = fmaf(m_, attv[q], e1);
      }
      e0 = red32(e0); e1 = red32(e1);
      float pe0 = __expf(e0), pe1 = __expf(e1);
      denom += pe0 + pe1;
#pragma unroll
      for (int q = 0; q < 4; ++q)
        num[q] = fmaf(pe1, b2f(v1[q]), fmaf(pe0, b2f(v0[q]), num[q]));
    }
    if (p < degc) {
      int s0 = __shfl(cv, p);
      { short4v v_ = *(const short4v*)(xb + (size_t)s0 * 400);
        float e_ = 0.f;
#pragma unroll
        for (int q = 0; q < 4; ++q) {
          float x_ = b2f(v_[q]); float m_ = x_ + xrv[q];
          m_ = (m_ > 0.f) ? m_ : NEG * m_; e_ = fmaf(m_, attv[q], e_);
        }
        e_ = red32(e_);
        float p_ = __expf(e_); denom += p_;
#pragma unroll
        for (int q = 0; q < 4; ++q) num[q] = fmaf(p_, b2f(v_[q]), num[q]);
      }
    }
    for (int t = 64; t < deg; ++t) {
      int s = col[beg + t];
      { short4v v_ = *(const short4v*)(xb + (size_t)s * 400);
        float e_ = 0.f;
#pragma unroll
        for (int q = 0; q < 4; ++q) {
          float x_ = b2f(v_[q]); float m_ = x_ + xrv[q];
          m_ = (m_ > 0.f) ? m_ : NEG * m_; e_ = fmaf(m_, attv[q], e_);
        }
        e_ = red32(e_);
        float p_ = __expf(e_); denom += p_;
#pragma unroll
        for (int q = 0; q < 4; ++q) num[q] = fmaf(p_, b2f(v_[q]), num[q]);
      }
    }

    float invd = 1.f / denom;
    if (ll < 25) {
      size_t sb = (size_t)idx * UU;
      f32x4 uv = *(const f32x4*)(out + sb + c0);   // u gate parked by k_agg1
      f32x4 sv = *(const f32x4*)(st + sb + c0);
      f32x4 res;
#pragma unroll
      for (int q = 0; q < 4; ++q) {
        float o   = fmaf(num[q], invd, g0[q] + h0[q]);
        float cvh = tanhf(o);
        res[q] = uv[q] * sv[q] + (1.f - uv[q]) * cvh;
      }
      *(f32x4*)(out + sb + c0) = res;
    }
  }
}

// ---------------- launch ----------------

extern "C" void kernel_launch(void* const* d_in, const int* in_sizes, int n_in,
                              void* d_out, int out_size, void* d_ws, size_t ws_size,
                              hipStream_t stream) {
  const float* inp  = (const float*)d_in[0];
  const float* st   = (const float*)d_in[1];
  const int*   src  = (const int*)d_in[2];
  const int*   dst  = (const int*)d_in[3];
  const float* Wl1  = (const float*)d_in[4];
  const float* bl1  = (const float*)d_in[5];
  const float* Wr1  = (const float*)d_in[6];
  const float* br1  = (const float*)d_in[7];
  const float* att1 = (const float*)d_in[8];
  const float* bg1  = (const float*)d_in[9];
  const float* bias0= (const float*)d_in[10];
  const float* Wl2  = (const float*)d_in[11];
  const float* bl2  = (const float*)d_in[12];
  const float* Wr2  = (const float*)d_in[13];
  const float* br2  = (const float*)d_in[14];
  const float* att2 = (const float*)d_in[15];
  const float* bg2  = (const float*)d_in[16];
  const float* bias1= (const float*)d_in[17];

  const int N = NN;
  const int E = in_sizes[2];   // 160000

  short* X1  = (short*)d_ws;                       // NN*800 (pair-contiguous rows)
  short* X2  = X1;                                 // NN*400 (X1 dead by then)
  short* Aws = X1 + (size_t)NN * 800;              // MPAD*128 (linear rows)
  short* BT1 = Aws + (size_t)MPAD * 128;           // 512*128 (linear)
  short* BT2 = BT1 + 512 * 128;                    // 256*128 (linear)
  int* rowptr = (int*)(BT2 + 256 * 128);
  int* cursor = rowptr + (N + 1);
  int* col    = cursor + N;

  // 1) prep (A1, BT1, BT2, cursor=0)
  k_prep<<<(MT * 16 + 255) / 256, 256, 0, stream>>>(inp, st, Wl1, Wr1, Wl2, Wr2,
                                                    Aws, BT1, BT2, cursor);
  // 2) gemm1 (+ fused hist in trailing blocks)
  {
    int nbg = 157 * 4;
    int nbh = (E + 255) / 256;
    k_gemmd<400, 200, 2><<<nbg + nbh, 256, 0, stream>>>(Aws, BT1, bl1, br1, X1,
                                                        nbg, dst, E, cursor);
  }
  // 3) scan  4) scatter
  k_scan<<<1, 1024, 0, stream>>>(cursor, rowptr, N, E);
  k_scatter<<<(E + 255) / 256, 256, 0, stream>>>(src, dst, E, cursor, col);
  // 5) agg1 (persistent waves)
  k_agg1<<<1024, 256, 0, stream>>>(X1, rowptr, col, att1, bg1, bias0, st, inp,
                                   Aws, (float*)d_out);
  // 6) gemm2 (no hist blocks)
  k_gemmd<200, 100, 2><<<157 * 2, 256, 0, stream>>>(Aws, BT2, bl2, br2, X2,
                                                    157 * 2, nullptr, 0, nullptr);
  // 7) agg2 (persistent waves)
  k_agg2<<<1024, 256, 0, stream>>>(X2, rowptr, col, att2, bg2, bias1, st,
                                   (float*)d_out);
}

// Round 13
// 176.885 us; speedup vs baseline: 1.0335x; 1.0335x over previous
//
#include <hip/hip_runtime.h>
#include <stdint.h>

typedef __attribute__((ext_vector_type(8))) short short8;   // 8 bf16 (bit pattern)
typedef __attribute__((ext_vector_type(4))) short short4v;  // 4 bf16
typedef __attribute__((ext_vector_type(4))) float f32x4;

static constexpr int BB = 2, NN = 20000, UU = 100;
static constexpr int MT = BB * NN;       // 40000 node-rows
static constexpr int MPAD = 40192;       // 157 * 256
static constexpr float NEG = 0.2f;

__device__ __forceinline__ float b2f(short s) {
  union { uint32_t u; float f; } cv; cv.u = ((uint32_t)(uint16_t)s) << 16; return cv.f;
}
__device__ __forceinline__ short f2b(float x) {             // RNE f32->bf16
  union { float f; uint32_t u; } cv; cv.f = x;
  uint32_t r = cv.u + 0x7FFFu + ((cv.u >> 16) & 1u);
  return (short)(r >> 16);
}

// DPP row_ror add: x += rotate-within-16-lanes(x). VALU-latency lane exchange.
template<int CTRL>
__device__ __forceinline__ float dppadd(float x) {
  int v = __builtin_amdgcn_update_dpp(0, __float_as_int(x), CTRL, 0xF, 0xF, false);
  return x + __int_as_float(v);
}
// sum over each 32-lane half: 4 DPP ror stages (16-lane sum) + 1 xor16
__device__ __forceinline__ float red32(float x) {
  x = dppadd<0x121>(x);   // row_ror:1
  x = dppadd<0x122>(x);   // row_ror:2
  x = dppadd<0x124>(x);   // row_ror:4
  x = dppadd<0x128>(x);   // row_ror:8
  return x + __shfl_xor(x, 16);
}

// ---------------- fused prep: zero cursor + build A1 + build BT1/BT2 (all LINEAR) ----

__global__ void k_prep(const float* __restrict__ inp, const float* __restrict__ st,
                       const float* __restrict__ Wl1, const float* __restrict__ Wr1,
                       const float* __restrict__ Wl2, const float* __restrict__ Wr2,
                       short* __restrict__ A, short* __restrict__ BT1,
                       short* __restrict__ BT2, int* __restrict__ cursor) {
  int t = blockIdx.x * 256 + threadIdx.x;
  if (t < MT * 16) {              // A1 row r: e0=inp, e1..100=state, pad 0
    int r = t >> 4, g = t & 15;
    short8 v;
#pragma unroll
    for (int j = 0; j < 8; ++j) {
      int e = g * 8 + j;
      float x = 0.f;
      if (e == 0) x = inp[r];
      else if (e <= 100) x = st[(size_t)r * 100 + e - 1];
      v[j] = f2b(x);
    }
    *(short8*)(A + (size_t)r * 128 + (g << 3)) = v;
  }
  if (t < 512 * 16) {             // BT1 (SPLIT=200)
    int n = t >> 4, g = t & 15;
    short8 v;
#pragma unroll
    for (int j = 0; j < 8; ++j) {
      int k = g * 8 + j;
      float x = 0.f;
      if (k < 101 && n < 400)
        x = (n < 200) ? Wl1[(size_t)k * 200 + n] : Wr1[(size_t)k * 200 + n - 200];
      v[j] = f2b(x);
    }
    *(short8*)(BT1 + (size_t)n * 128 + (g << 3)) = v;
  }
  if (t < 256 * 16) {             // BT2 (rot: k<100 -> W[k+1], k==100 -> W[0])
    int n = t >> 4, g = t & 15;
    short8 v;
#pragma unroll
    for (int j = 0; j < 8; ++j) {
      int k = g * 8 + j;
      int ksrc = (k < 100) ? k + 1 : ((k == 100) ? 0 : -1);
      float x = 0.f;
      if (ksrc >= 0 && n < 200)
        x = (n < 100) ? Wl2[(size_t)ksrc * 100 + n] : Wr2[(size_t)ksrc * 100 + n - 100];
      v[j] = f2b(x);
    }
    *(short8*)(BT2 + (size_t)n * 128 + (g << 3)) = v;
  }
  if (t < NN) cursor[t] = 0;
}

// ---------------- CSR build ----------------

__global__ __launch_bounds__(1024) void k_scan(int* __restrict__ histcur,
                                               int* __restrict__ rowptr, int N, int E) {
  __shared__ int part[1024];
  int t = threadIdx.x;
  int CH = (N + 1023) / 1024;
  int beg = t * CH; if (beg > N) beg = N;
  int end = beg + CH; if (end > N) end = N;
  int s = 0;
  for (int i = beg; i < end; ++i) s += histcur[i];
  part[t] = s;
  __syncthreads();
  for (int off = 1; off < 1024; off <<= 1) {
    int v = (t >= off) ? part[t - off] : 0;
    __syncthreads();
    part[t] += v;
    __syncthreads();
  }
  int base = (t == 0) ? 0 : part[t - 1];
  for (int i = beg; i < end; ++i) {
    int h = histcur[i];
    rowptr[i] = base;
    histcur[i] = base;
    base += h;
  }
  if (t == 1023) rowptr[N] = part[1023];
}

__global__ void k_scatter(const int* __restrict__ src, const int* __restrict__ dst, int E,
                          int* __restrict__ cursor, int* __restrict__ col) {
  int e = blockIdx.x * 256 + threadIdx.x;
  if (e < E) {
    int p = atomicAdd(&cursor[dst[e]], 1);
    col[p] = src[e];
  }
}

// ---------------- no-LDS direct-fragment MFMA GEMM, swapped operands ----------------
// Outputs SPLIT to XL table [node][xl_b0|xl_b1] and XR table [node][xr_b0|xr_b1]
// (2*SPLIT shorts per row each) — gathered xl rows are dense (no xr interleave).
// Trailing blocks (>= nbg) run the edge histogram (layer-1 launch only).

template<int NOUT, int SPLIT, int NTW>
__global__ __launch_bounds__(256) void k_gemmd(
    const short* __restrict__ A, const short* __restrict__ BT,
    const float* __restrict__ bias_l, const float* __restrict__ bias_r,
    short* __restrict__ XL, short* __restrict__ XR, int nbg,
    const int* __restrict__ dstE, int E, int* __restrict__ hist) {
  int tid = threadIdx.x;
  if ((int)blockIdx.x >= nbg) {   // fused histogram blocks
    int e = (blockIdx.x - nbg) * 256 + tid;
    if (e < E) atomicAdd(&hist[dstE[e]], 1);
    return;
  }
  int bx = blockIdx.x % 157, by = blockIdx.x / 157;
  int w = tid >> 6, lane = tid & 63;
  int m0 = (bx * 4 + w) * 64;
  int lrow = lane & 15, lk = lane >> 4;

  short8 a[4][4];                 // [kk][j] node fragments, persist across n-tiles
#pragma unroll
  for (int kk = 0; kk < 4; ++kk)
#pragma unroll
    for (int j = 0; j < 4; ++j)
      a[kk][j] = *(const short8*)(A + ((size_t)m0 + j * 16 + lrow) * 128 + lk * 8 + kk * 32);

#pragma unroll
  for (int nt = 0; nt < NTW; ++nt) {
    int nbase = (by * NTW + nt) * 64;
    f32x4 acc[4][4];              // [i=ch-subtile][j=node-subtile]
#pragma unroll
    for (int i = 0; i < 4; ++i)
#pragma unroll
      for (int j = 0; j < 4; ++j) acc[i][j] = (f32x4){0.f, 0.f, 0.f, 0.f};

#pragma unroll
    for (int kk = 0; kk < 4; ++kk) {
      short8 b[4];
#pragma unroll
      for (int i = 0; i < 4; ++i)
        b[i] = *(const short8*)(BT + ((size_t)nbase + i * 16 + lrow) * 128 + lk * 8 + kk * 32);
#pragma unroll
      for (int i = 0; i < 4; ++i)
#pragma unroll
        for (int j = 0; j < 4; ++j)
          acc[i][j] = __builtin_amdgcn_mfma_f32_16x16x32_bf16(b[i], a[kk][j], acc[i][j], 0, 0, 0);
    }

#pragma unroll
    for (int i = 0; i < 4; ++i) {
      int ch = nbase + i * 16 + lk * 4;       // 4 consecutive channels (ch..ch+3)
      if (ch < NOUT) {
        bool isl = ch < SPLIT;
        f32x4 bv = isl ? *(const f32x4*)(bias_l + ch)
                       : *(const f32x4*)(bias_r + (ch - SPLIT));
        short* Xp = isl ? XL : XR;
        int cb    = isl ? ch : ch - SPLIT;
#pragma unroll
        for (int j = 0; j < 4; ++j) {
          int m = m0 + j * 16 + lrow;
          if (m < MT) {
            int b_   = (m >= NN) ? 1 : 0;
            int node = m - b_ * NN;
            short4v wv;
#pragma unroll
            for (int r = 0; r < 4; ++r) wv[r] = f2b(acc[i][j][r] + bv[r]);
            *(short4v*)(Xp + (size_t)node * (2 * SPLIT) + cb + b_ * SPLIT) = wv;
          }
        }
      }
    }
  }
}

// ---------------- GATv2 aggregation: persistent waves, 2-edge unroll, DPP reduce ----
// lanes 0-31 = batch 0, 32-63 = batch 1; lane owns 8 (agg1) / 4 (agg2) channels.
// No-max softmax: logits bounded (|e| << 88), exp safe in fp32.
// XL table gathered per edge (dense 800B/400B rows); XR read once per dst.

#define EDGE1(S, NUM, DEN, NCH, STRIDE)                                            \
  { short8 v_ = *(const short8*)(xb + (size_t)(S) * STRIDE);                       \
    float e_ = 0.f;                                                                \
    _Pragma("unroll") for (int q = 0; q < NCH; ++q) {                              \
      float x_ = b2f(v_[q]); float m_ = x_ + xrv[q];                               \
      m_ = (m_ > 0.f) ? m_ : NEG * m_; e_ = fmaf(m_, attv[q], e_); }               \
    e_ = red32(e_);                                                                \
    float p_ = __expf(e_); DEN += p_;                                              \
    _Pragma("unroll") for (int q = 0; q < NCH; ++q)                                \
      NUM[q] = fmaf(p_, b2f(v_[q]), NUM[q]); }

__global__ __launch_bounds__(256) void k_agg1(
    const short* __restrict__ XL1, const short* __restrict__ XR1,
    const int* __restrict__ rowptr, const int* __restrict__ col,
    const float* __restrict__ att, const float* __restrict__ bgv, const float* __restrict__ bias0,
    const float* __restrict__ st, const float* __restrict__ inp,
    short* __restrict__ A2, float* __restrict__ uu) {
  int lane = threadIdx.x & 63;
  int gw = blockIdx.x * 4 + (threadIdx.x >> 6);
  int NW = gridDim.x * 4;
  int half = lane >> 5, ll = lane & 31;
  int c0 = (ll < 25 ? ll : 24) * 8;
  const short* xb = XL1 + (size_t)half * 200 + c0;   // + s*400 per src node

  float attv[8];
  f32x4 g0 = (f32x4){0,0,0,0}, g1 = (f32x4){0,0,0,0};
  f32x4 h0 = (f32x4){0,0,0,0}, h1 = (f32x4){0,0,0,0};
  {
    f32x4 a0 = (f32x4){0,0,0,0}, a1 = (f32x4){0,0,0,0};
    if (ll < 25) {
      a0 = *(const f32x4*)(att + c0);   a1 = *(const f32x4*)(att + c0 + 4);
      g0 = *(const f32x4*)(bgv + c0);   g1 = *(const f32x4*)(bgv + c0 + 4);
      h0 = *(const f32x4*)(bias0 + c0); h1 = *(const f32x4*)(bias0 + c0 + 4);
    }
#pragma unroll
    for (int q = 0; q < 4; ++q) { attv[q] = a0[q]; attv[4 + q] = a1[q]; }
  }

  for (int n = gw; n < NN; n += NW) {
    int idx = half * NN + n;
    float xrv[8], num[8];
    {
      short8 xr8 = *(const short8*)(XR1 + (size_t)n * 400 + half * 200 + c0);
#pragma unroll
      for (int q = 0; q < 8; ++q) xrv[q] = (ll < 25) ? b2f(xr8[q]) : 0.f;
    }
    float denom;
    { // self-loop (src = n)
      short8 v = *(const short8*)(xb + (size_t)n * 400);
      float xs[8], e = 0.f;
#pragma unroll
      for (int q = 0; q < 8; ++q) {
        xs[q] = b2f(v[q]);
        float msg = xs[q] + xrv[q];
        msg = (msg > 0.f) ? msg : NEG * msg;
        e = fmaf(msg, attv[q], e);
      }
      e = red32(e);
      float pe = __expf(e);
      denom = pe;
#pragma unroll
      for (int q = 0; q < 8; ++q) num[q] = pe * xs[q];
    }

    int beg = rowptr[n], end = rowptr[n + 1];
    int deg = end - beg;
    int degc = min(deg, 64);
    int cv = 0;
    if (deg > 0) cv = col[beg + (lane < degc ? lane : 0)];
    int p = 0;
    for (; p + 2 <= degc; p += 2) {          // 2 independent chains
      int s0 = __shfl(cv, p), s1 = __shfl(cv, p + 1);
      short8 v0 = *(const short8*)(xb + (size_t)s0 * 400);
      short8 v1 = *(const short8*)(xb + (size_t)s1 * 400);
      float e0 = 0.f, e1 = 0.f;
#pragma unroll
      for (int q = 0; q < 8; ++q) {
        float x, m_;
        x = b2f(v0[q]); m_ = x + xrv[q]; m_ = (m_ > 0.f) ? m_ : NEG * m_; e0 = fmaf(m_, attv[q], e0);
        x = b2f(v1[q]); m_ = x + xrv[q]; m_ = (m_ > 0.f) ? m_ : NEG * m_; e1 = fmaf(m_, attv[q], e1);
      }
      e0 = red32(e0); e1 = red32(e1);
      float pe0 = __expf(e0), pe1 = __expf(e1);
      denom += pe0 + pe1;
#pragma unroll
      for (int q = 0; q < 8; ++q)
        num[q] = fmaf(pe1, b2f(v1[q]), fmaf(pe0, b2f(v0[q]), num[q]));
    }
    if (p < degc) {
      int s0 = __shfl(cv, p);
      EDGE1(s0, num, denom, 8, 400);
    }
    for (int t = 64; t < deg; ++t) { int s = col[beg + t]; EDGE1(s, num, denom, 8, 400); }

    float invd = 1.f / denom;
    if (ll < 25) {
      float vq[8];
#pragma unroll
      for (int q = 0; q < 4; ++q) {
        float o0 = fmaf(num[q], invd, g0[q] + h0[q]);
        vq[q] = 1.f / (1.f + __expf(-o0));
        float o1 = fmaf(num[4 + q], invd, g1[q] + h1[q]);
        vq[4 + q] = 1.f / (1.f + __expf(-o1));
      }
      size_t sb = (size_t)idx * UU;
      if (ll < 12) {                       // 8 r*state channels -> A2 granule ll (linear)
        f32x4 s0 = *(const f32x4*)(st + sb + c0), s1 = *(const f32x4*)(st + sb + c0 + 4);
        short8 wv;
#pragma unroll
        for (int q = 0; q < 4; ++q) { wv[q] = f2b(vq[q] * s0[q]); wv[4 + q] = f2b(vq[4 + q] * s1[q]); }
        *(short8*)(A2 + (size_t)idx * 128 + (ll << 3)) = wv;
      } else if (ll == 12) {               // ch 96-99 rs + elem100 = inp + pad
        f32x4 s0 = *(const f32x4*)(st + sb + 96);
        short8 wv;
#pragma unroll
        for (int q = 0; q < 4; ++q) wv[q] = f2b(vq[q] * s0[q]);
        wv[4] = f2b(inp[idx]); wv[5] = 0; wv[6] = 0; wv[7] = 0;
        *(short8*)(A2 + (size_t)idx * 128 + (12 << 3)) = wv;
        *(f32x4*)(uu + sb) = (f32x4){vq[4], vq[5], vq[6], vq[7]};
      } else {                             // 8 u channels; ll 13-15 also zero-pad A2
        int uo = c0 - 100;
        *(f32x4*)(uu + sb + uo)     = (f32x4){vq[0], vq[1], vq[2], vq[3]};
        *(f32x4*)(uu + sb + uo + 4) = (f32x4){vq[4], vq[5], vq[6], vq[7]};
        if (ll < 16) {
          short8 z = (short8){0,0,0,0,0,0,0,0};
          *(short8*)(A2 + (size_t)idx * 128 + (ll << 3)) = z;
        }
      }
    }
  }
}

__global__ __launch_bounds__(256) void k_agg2(
    const short* __restrict__ XL2, const short* __restrict__ XR2,
    const int* __restrict__ rowptr, const int* __restrict__ col,
    const float* __restrict__ att, const float* __restrict__ bgv, const float* __restrict__ bias1,
    const float* __restrict__ st, float* __restrict__ out) {
  int lane = threadIdx.x & 63;
  int gw = blockIdx.x * 4 + (threadIdx.x >> 6);
  int NW = gridDim.x * 4;
  int half = lane >> 5, ll = lane & 31;
  int c0 = (ll < 25 ? ll : 24) * 4;
  const short* xb = XL2 + (size_t)half * 100 + c0;   // + s*200 per src node

  float attv[4];
  f32x4 g0 = (f32x4){0,0,0,0}, h0 = (f32x4){0,0,0,0};
  {
    f32x4 a0 = (f32x4){0,0,0,0};
    if (ll < 25) {
      a0 = *(const f32x4*)(att + c0);
      g0 = *(const f32x4*)(bgv + c0);
      h0 = *(const f32x4*)(bias1 + c0);
    }
#pragma unroll
    for (int q = 0; q < 4; ++q) attv[q] = a0[q];
  }

  for (int n = gw; n < NN; n += NW) {
    int idx = half * NN + n;
    float xrv[4], num[4];
    {
      short4v xr4 = *(const short4v*)(XR2 + (size_t)n * 200 + half * 100 + c0);
#pragma unroll
      for (int q = 0; q < 4; ++q) xrv[q] = (ll < 25) ? b2f(xr4[q]) : 0.f;
    }
    float denom;
    { // self-loop
      short4v v = *(const short4v*)(xb + (size_t)n * 200);
      float xs[4], e = 0.f;
#pragma unroll
      for (int q = 0; q < 4; ++q) {
        xs[q] = b2f(v[q]);
        float msg = xs[q] + xrv[q];
        msg = (msg > 0.f) ? msg : NEG * msg;
        e = fmaf(msg, attv[q], e);
      }
      e = red32(e);
      float pe = __expf(e);
      denom = pe;
#pragma unroll
      for (int q = 0; q < 4; ++q) num[q] = pe * xs[q];
    }

    int beg = rowptr[n], end = rowptr[n + 1];
    int deg = end - beg;
    int degc = min(deg, 64);
    int cv = 0;
    if (deg > 0) cv = col[beg + (lane < degc ? lane : 0)];
    int p = 0;
    for (; p + 2 <= degc; p += 2) {
      int s0 = __shfl(cv, p), s1 = __shfl(cv, p + 1);
      short4v v0 = *(const short4v*)(xb + (size_t)s0 * 200);
      short4v v1 = *(const short4v*)(xb + (size_t)s1 * 200);
      float e0 = 0.f, e1 = 0.f;
#pragma unroll
      for (int q = 0; q < 4; ++q) {
        float x, m_;
        x = b2f(v0[q]); m_ = x + xrv[q]; m_ = (m_ > 0.f) ? m_ : NEG * m_; e0 = fmaf(m_, attv[q], e0);
        x = b2f(v1[q]); m_ = x + xrv[q]; m_ = (m_ > 0.f) ? m_ : NEG * m_; e1 = fmaf(m_, attv[q], e1);
      }
      e0 = red32(e0); e1 = red32(e1);
      float pe0 = __expf(e0), pe1 = __expf(e1);
      denom += pe0 + pe1;
#pragma unroll
      for (int q = 0; q < 4; ++q)
        num[q] = fmaf(pe1, b2f(v1[q]), fmaf(pe0, b2f(v0[q]), num[q]));
    }
    if (p < degc) {
      int s0 = __shfl(cv, p);
      { short4v v_ = *(const short4v*)(xb + (size_t)s0 * 200);
        float e_ = 0.f;
#pragma unroll
        for (int q = 0; q < 4; ++q) {
          float x_ = b2f(v_[q]); float m_ = x_ + xrv[q];
          m_ = (m_ > 0.f) ? m_ : NEG * m_; e_ = fmaf(m_, attv[q], e_);
        }
        e_ = red32(e_);
        float p_ = __expf(e_); denom += p_;
#pragma unroll
        for (int q = 0; q < 4; ++q) num[q] = fmaf(p_, b2f(v_[q]), num[q]);
      }
    }
    for (int t = 64; t < deg; ++t) {
      int s = col[beg + t];
      { short4v v_ = *(const short4v*)(xb + (size_t)s * 200);
        float e_ = 0.f;
#pragma unroll
        for (int q = 0; q < 4; ++q) {
          float x_ = b2f(v_[q]); float m_ = x_ + xrv[q];
          m_ = (m_ > 0.f) ? m_ : NEG * m_; e_ = fmaf(m_, attv[q], e_);
        }
        e_ = red32(e_);
        float p_ = __expf(e_); denom += p_;
#pragma unroll
        for (int q = 0; q < 4; ++q) num[q] = fmaf(p_, b2f(v_[q]), num[q]);
      }
    }

    float invd = 1.f / denom;
    if (ll < 25) {
      size_t sb = (size_t)idx * UU;
      f32x4 uv = *(const f32x4*)(out + sb + c0);   // u gate parked by k_agg1
      f32x4 sv = *(const f32x4*)(st + sb + c0);
      f32x4 res;
#pragma unroll
      for (int q = 0; q < 4; ++q) {
        float o   = fmaf(num[q], invd, g0[q] + h0[q]);
        float cvh = tanhf(o);
        res[q] = uv[q] * sv[q] + (1.f - uv[q]) * cvh;
      }
      *(f32x4*)(out + sb + c0) = res;
    }
  }
}

// ---------------- launch ----------------

extern "C" void kernel_launch(void* const* d_in, const int* in_sizes, int n_in,
                              void* d_out, int out_size, void* d_ws, size_t ws_size,
                              hipStream_t stream) {
  const float* inp  = (const float*)d_in[0];
  const float* st   = (const float*)d_in[1];
  const int*   src  = (const int*)d_in[2];
  const int*   dst  = (const int*)d_in[3];
  const float* Wl1  = (const float*)d_in[4];
  const float* bl1  = (const float*)d_in[5];
  const float* Wr1  = (const float*)d_in[6];
  const float* br1  = (const float*)d_in[7];
  const float* att1 = (const float*)d_in[8];
  const float* bg1  = (const float*)d_in[9];
  const float* bias0= (const float*)d_in[10];
  const float* Wl2  = (const float*)d_in[11];
  const float* bl2  = (const float*)d_in[12];
  const float* Wr2  = (const float*)d_in[13];
  const float* br2  = (const float*)d_in[14];
  const float* att2 = (const float*)d_in[15];
  const float* bg2  = (const float*)d_in[16];
  const float* bias1= (const float*)d_in[17];

  const int N = NN;
  const int E = in_sizes[2];   // 160000

  // ws: XL1[16MB] | XR1[16MB] | A[10.3MB] | BT1 | BT2 | CSR.
  // layer 2: XL2/XR2 alias XL1 front (XL1 dead after agg1).
  short* XL1 = (short*)d_ws;                       // NN*400 shorts
  short* XR1 = XL1 + (size_t)NN * 400;             // NN*400 shorts
  short* Aws = XR1 + (size_t)NN * 400;             // MPAD*128 (linear rows)
  short* BT1 = Aws + (size_t)MPAD * 128;           // 512*128 (linear)
  short* BT2 = BT1 + 512 * 128;                    // 256*128 (linear)
  int* rowptr = (int*)(BT2 + 256 * 128);
  int* cursor = rowptr + (N + 1);
  int* col    = cursor + N;
  short* XL2 = XL1;                                // NN*200 shorts
  short* XR2 = XL1 + (size_t)NN * 200;             // NN*200 shorts

  // 1) prep (A1, BT1, BT2, cursor=0)
  k_prep<<<(MT * 16 + 255) / 256, 256, 0, stream>>>(inp, st, Wl1, Wr1, Wl2, Wr2,
                                                    Aws, BT1, BT2, cursor);
  // 2) gemm1 (+ fused hist in trailing blocks)
  {
    int nbg = 157 * 4;
    int nbh = (E + 255) / 256;
    k_gemmd<400, 200, 2><<<nbg + nbh, 256, 0, stream>>>(Aws, BT1, bl1, br1, XL1, XR1,
                                                        nbg, dst, E, cursor);
  }
  // 3) scan  4) scatter
  k_scan<<<1, 1024, 0, stream>>>(cursor, rowptr, N, E);
  k_scatter<<<(E + 255) / 256, 256, 0, stream>>>(src, dst, E, cursor, col);
  // 5) agg1 (persistent waves, 2x grid)
  k_agg1<<<2048, 256, 0, stream>>>(XL1, XR1, rowptr, col, att1, bg1, bias0, st, inp,
                                   Aws, (float*)d_out);
  // 6) gemm2 (no hist blocks)
  k_gemmd<200, 100, 2><<<157 * 2, 256, 0, stream>>>(Aws, BT2, bl2, br2, XL2, XR2,
                                                    157 * 2, nullptr, 0, nullptr);
  // 7) agg2 (persistent waves, 2x grid)
  k_agg2<<<2048, 256, 0, stream>>>(XL2, XR2, rowptr, col, att2, bg2, bias1, st,
                                   (float*)d_out);
}